// Round 1
// 337.807 us; speedup vs baseline: 1.0308x; 1.0308x over previous
//
#include <hip/hip_runtime.h>
#include <hip/hip_bf16.h>

#define NN 100000
#define NE 625000
#define HH 128
#define DOUT 64
#define NHTOT (NN * HH)          // 12,800,000 feature elements
#define SCAN_B 391               // ceil(NN/256)
#define WTOT 107712              // canonical weight element count

// merged-prep block ranges
#define NB_CVT  12500            // NHTOT/4/256 exact
#define NB_CVTW 421              // ceil(WTOT/256)
#define NB_HIST 2442             // ceil(NE/256)

// canonical weight offsets (elements)
#define OW_Wl  0
#define OW_bl  49152
#define OW_Wr  49536
#define OW_gam 98688
#define OW_bet 99072
#define OW_Wo  99456
#define OW_bo  107648

typedef unsigned int u32;
typedef unsigned short u16;
typedef long long i64;
typedef short bf16x8 __attribute__((ext_vector_type(8)));   // 8 bf16 = 4 VGPR
typedef float f32x4 __attribute__((ext_vector_type(4)));

__device__ __forceinline__ float bflo(u32 v) { return __uint_as_float(v << 16); }
__device__ __forceinline__ float bfhi(u32 v) { return __uint_as_float(v & 0xffff0000u); }
__device__ __forceinline__ float bf2f(u16 u) { return __uint_as_float(((u32)u) << 16); }
__device__ __forceinline__ u16 f2b(float f) {
    __hip_bfloat16 h = __float2bfloat16(f);   // RNE
    return *(u16*)&h;
}
__device__ __forceinline__ int edge_at(const void* ei, int is64, i64 idx) {
    return is64 ? (int)((const i64*)ei)[idx] : ((const int*)ei)[idx];
}

// ---- block 0: dtype sniffer (flags[0]=x is fp32, flags[1]=edges int64)
// ---- blocks 1..391: zero cnt; also zero the scan global base ----
__global__ void k_sz(const u16* __restrict__ x, const int* __restrict__ ei,
                     int* __restrict__ flags, int* __restrict__ cnt,
                     int* __restrict__ gbase) {
    int t = threadIdx.x;
    if (blockIdx.x == 0) {
        __shared__ int cbad, cnz;
        if (t == 0) { cbad = 0; cnz = 0; }
        __syncthreads();
        u16 u = x[t];
        int e = (u >> 7) & 0xff;            // bf16 exponent field
        if (e >= 132) atomicAdd(&cbad, 1);
        if (t < 32) { if (ei[2 * t + 1] != 0) atomicAdd(&cnz, 1); }
        __syncthreads();
        if (t == 0) {
            flags[0] = (cbad > 4) ? 1 : 0;  // fp32 floats
            flags[1] = (cnz == 0) ? 1 : 0;  // int64 edges
            gbase[0] = 0;
        }
    } else {
        int g = (blockIdx.x - 1) * 256 + t;
        if (g < NN) cnt[g] = 0;
    }
}

// ---- merged prep: x->bf16 cvt | weight canonicalize (+I fold) | degree hist ----
__global__ void k_prep(const void* __restrict__ xin, uint2* __restrict__ xc,
                       const void* Wl, const void* bl, const void* Wr,
                       const void* gam, const void* bet, const void* Wo,
                       const void* bo, u16* __restrict__ wc,
                       const void* __restrict__ ei, int* __restrict__ cnt,
                       const int* __restrict__ flags) {
    int b = blockIdx.x, t = threadIdx.x;
    if (b < NB_CVT) {
        int gid = b * 256 + t;                       // grid exact
        if (flags[0]) {
            float4 v = ((const float4*)xin)[gid];
            uint2 r;
            r.x = (u32)f2b(v.x) | ((u32)f2b(v.y) << 16);
            r.y = (u32)f2b(v.z) | ((u32)f2b(v.w) << 16);
            xc[gid] = r;
        } else {
            xc[gid] = ((const uint2*)xin)[gid];
        }
    } else if (b < NB_CVT + NB_CVTW) {
        int gid = (b - NB_CVT) * 256 + t;
        if (gid >= WTOT) return;
        const void* p; int li; float add = 0.f;
        if      (gid < OW_bl)  { p = Wl;  li = gid; }
        else if (gid < OW_Wr)  { p = bl;  li = gid - OW_bl; }
        else if (gid < OW_gam) { p = Wr;  li = gid - OW_Wr;
                                 int lay = li >> 14, rc = li & 16383;
                                 if (lay > 0 && (rc >> 7) == (rc & 127)) add = 1.0f; }
        else if (gid < OW_bet) { p = gam; li = gid - OW_gam; }
        else if (gid < OW_Wo)  { p = bet; li = gid - OW_bet; }
        else if (gid < OW_bo)  { p = Wo;  li = gid - OW_Wo; }
        else                   { p = bo;  li = gid - OW_bo; }
        float v = flags[0] ? ((const float*)p)[li] : bf2f(((const u16*)p)[li]);
        wc[gid] = f2b(v + add);
    } else {
        int e = (b - NB_CVT - NB_CVTW) * 256 + t;
        if (e < NE) {
            int d = edge_at(ei, flags[1], (i64)NE + e);
            if ((unsigned)d < NN) atomicAdd(&cnt[d], 1);
        }
    }
}

// ---- single-pass offsets: block scan + atomic global base (order-free CSR) ----
__global__ void k_offs(const int* __restrict__ cnt, int* __restrict__ gbase,
                       int* __restrict__ offs, int* __restrict__ cur,
                       float* __restrict__ invdeg) {
    __shared__ int sh[256];
    __shared__ int sbase;
    int t = threadIdx.x, g = blockIdx.x * 256 + t;
    int c = (g < NN) ? cnt[g] : 0;
    sh[t] = c; __syncthreads();
    for (int off = 1; off < 256; off <<= 1) {
        int a = (t >= off) ? sh[t - off] : 0;
        __syncthreads(); sh[t] += a; __syncthreads();
    }
    if (t == 255) sbase = atomicAdd(gbase, sh[255]);
    __syncthreads();
    if (g < NN) {
        int start = sbase + sh[t] - c;
        offs[g] = start; cur[g] = start;
        invdeg[g] = 1.0f / fmaxf((float)c, 1.0f);
    }
}

// ---- counting-sort src by dst ----
__global__ void k_sort(const void* __restrict__ ei, int* __restrict__ cur,
                       int* __restrict__ ssrc, const int* __restrict__ flags) {
    int e = blockIdx.x * 256 + threadIdx.x;
    if (e < NE) {
        int is64 = flags[1];
        int d = edge_at(ei, is64, (i64)NE + e);
        int s = edge_at(ei, is64, (i64)e);
        if ((unsigned)d < NN) {
            int p = atomicAdd(&cur[d], 1);
            if ((unsigned)p < NE) ssrc[p] = s;
        }
    }
}

// ---- aggregation: 4 nodes/wave (16-lane groups), masked 8-wide rounds ----
// Every chunk processed as ceil(rem/8) rounds of 8 clamped loads + mask-FMA:
// no serial per-edge tail, max 2 exposed latencies for deg<=8 (most nodes).
__global__ void k_agg(const bf16x8* __restrict__ Xv, const int* __restrict__ offs,
                      const int* __restrict__ cnt, const int* __restrict__ ssrc,
                      const float* __restrict__ invdeg, bf16x8* __restrict__ AGGv) {
    int node = (blockIdx.x * 256 + threadIdx.x) >> 4;   // grid exact: NN*16/256
    int gl = threadIdx.x & 15;
    int s0 = offs[node], c = cnt[node];
    float iv = invdeg[node];
    float a[8];
    #pragma unroll
    for (int e = 0; e < 8; ++e) a[e] = 0.f;
    for (int base = 0; base < c; base += 16) {
        int rem = min(16, c - base);
        int idx = ssrc[s0 + base + min(gl, rem - 1)];   // coalesced index prefetch
        idx = min(max(idx, 0), NN - 1);
        for (int j = 0; j < rem; j += 8) {
            bf16x8 v[8]; float m[8];
            #pragma unroll
            for (int k = 0; k < 8; ++k) {
                int jj = j + k;
                int ii = __shfl(idx, min(jj, rem - 1), 16);
                m[k] = (jj < rem) ? 1.f : 0.f;
                v[k] = Xv[(size_t)ii * 16 + gl];
            }
            #pragma unroll
            for (int k = 0; k < 8; ++k)
                #pragma unroll
                for (int e = 0; e < 8; ++e)
                    a[e] = fmaf(m[k], bf2f((u16)v[k][e]), a[e]);
        }
    }
    bf16x8 r;
    #pragma unroll
    for (int e = 0; e < 8; ++e) r[e] = (short)f2b(a[e] * iv);
    AGGv[(size_t)node * 16 + gl] = r;
}

// ---- MFMA fused dual-GEMM + bias + LN + ReLU (+optional fused projection) ----
// Block = 256 thr / 4 waves / 128 nodes. A tiles staged via 32 KB swizzled
// LDS; W staged in 32 KB halves. FUSE=1: h3 round-trips through the A-LDS
// (C-layout -> A-layout), Wo restaged into WS, out written directly.
template <int FUSE>
__global__ __launch_bounds__(256, 2) void k_gemm(
        const u16* __restrict__ X, u16* __restrict__ AGG,
        const u16* __restrict__ Wl, const u16* __restrict__ Wr,
        const u16* __restrict__ bl, const u16* __restrict__ gam,
        const u16* __restrict__ bet,
        const u16* __restrict__ Wo, const u16* __restrict__ bo,
        void* __restrict__ out, const int* __restrict__ flags) {
    __shared__ __align__(16) u16 WS[16384];   // 32 KB: one W matrix in frag order
    __shared__ __align__(16) u32 AS[8192];    // 32 KB: 128-node tile, chunk-XOR swizzle
    int tid = threadIdx.x;
    int wave = tid >> 6, lane = tid & 63;
    int mn = lane & 15, quad = lane >> 4;
    int n0 = blockIdx.x * 128;
    int n0w = n0 + wave * 32;

    // issue Wl + AGG-tile loads (each thread: 8 chunks of each, coalesced)
    bf16x8 wreg[8], areg[8];
    #pragma unroll
    for (int it = 0; it < 8; ++it) {
        int cid = it * 256 + tid;             // 0..2047
        int ft = cid >> 8, kt = (cid >> 6) & 3, q = (cid >> 4) & 3, f16 = cid & 15;
        wreg[it] = *(const bf16x8*)(Wl + (size_t)(ft * 16 + f16) * HH + kt * 32 + q * 8);
        int n = cid >> 4, c = cid & 15;
        int ng = min(n0 + n, NN - 1);
        areg[it] = *(const bf16x8*)(AGG + (size_t)ng * HH + c * 8);
    }
    #pragma unroll
    for (int it = 0; it < 8; ++it) {
        int cid = it * 256 + tid;
        int n = cid >> 4, c = cid & 15;
        *(bf16x8*)&WS[(size_t)cid * 8] = wreg[it];
        *(bf16x8*)&AS[(size_t)(n * 16 + (c ^ (n & 15))) * 4] = areg[it];
    }
    __syncthreads();

    // AGG A-frags from LDS; meanwhile issue Wr + X-tile loads
    bf16x8 afr[2][4];
    #pragma unroll
    for (int g = 0; g < 2; ++g) {
        int ln = wave * 32 + g * 16 + mn;
        #pragma unroll
        for (int kt = 0; kt < 4; ++kt)
            afr[g][kt] = *(const bf16x8*)&AS[(size_t)(ln * 16 + ((kt * 4 + quad) ^ mn)) * 4];
    }
    #pragma unroll
    for (int it = 0; it < 8; ++it) {
        int cid = it * 256 + tid;
        int ft = cid >> 8, kt = (cid >> 6) & 3, q = (cid >> 4) & 3, f16 = cid & 15;
        wreg[it] = *(const bf16x8*)(Wr + (size_t)(ft * 16 + f16) * HH + kt * 32 + q * 8);
        int n = cid >> 4, c = cid & 15;
        int ng = min(n0 + n, NN - 1);
        areg[it] = *(const bf16x8*)(X + (size_t)ng * HH + c * 8);
    }

    f32x4 acc[8][2];
    #pragma unroll
    for (int ft = 0; ft < 8; ++ft)
        #pragma unroll
        for (int g = 0; g < 2; ++g) acc[ft][g] = (f32x4){0.f, 0.f, 0.f, 0.f};

    int laneoff = (quad * 16 + mn) * 8;
    // phase 1: AGG @ Wl^T
    #pragma unroll
    for (int ft = 0; ft < 8; ++ft) {
        #pragma unroll
        for (int kt = 0; kt < 4; ++kt) {
            bf16x8 b = *(const bf16x8*)&WS[(ft * 4 + kt) * 512 + laneoff];
            acc[ft][0] = __builtin_amdgcn_mfma_f32_16x16x32_bf16(afr[0][kt], b, acc[ft][0], 0, 0, 0);
            acc[ft][1] = __builtin_amdgcn_mfma_f32_16x16x32_bf16(afr[1][kt], b, acc[ft][1], 0, 0, 0);
        }
    }

    __syncthreads();   // everyone done with Wl / AGG tile
    #pragma unroll
    for (int it = 0; it < 8; ++it) {
        int cid = it * 256 + tid;
        int n = cid >> 4, c = cid & 15;
        *(bf16x8*)&WS[(size_t)cid * 8] = wreg[it];
        *(bf16x8*)&AS[(size_t)(n * 16 + (c ^ (n & 15))) * 4] = areg[it];
    }
    __syncthreads();   // Wr + X tile staged

    #pragma unroll
    for (int g = 0; g < 2; ++g) {
        int ln = wave * 32 + g * 16 + mn;
        #pragma unroll
        for (int kt = 0; kt < 4; ++kt)
            afr[g][kt] = *(const bf16x8*)&AS[(size_t)(ln * 16 + ((kt * 4 + quad) ^ mn)) * 4];
    }
    // phase 2: X @ (Wr + I)^T   (residual folded)
    #pragma unroll
    for (int ft = 0; ft < 8; ++ft) {
        #pragma unroll
        for (int kt = 0; kt < 4; ++kt) {
            bf16x8 b = *(const bf16x8*)&WS[(ft * 4 + kt) * 512 + laneoff];
            acc[ft][0] = __builtin_amdgcn_mfma_f32_16x16x32_bf16(afr[0][kt], b, acc[ft][0], 0, 0, 0);
            acc[ft][1] = __builtin_amdgcn_mfma_f32_16x16x32_bf16(afr[1][kt], b, acc[ft][1], 0, 0, 0);
        }
    }

    if (FUSE) __syncthreads();   // AS free for h3 (all phase-2 frag reads done)

    // epilogue per node group: bias + LN + relu
    u16* AS2 = (u16*)AS;   // FUSE: h3 tile [128 nodes][128 feats], chunk-XOR swizzle
    #pragma unroll
    for (int g = 0; g < 2; ++g) {
        int nb = n0w + g * 16;
        float s1[4] = {0, 0, 0, 0}, s2[4] = {0, 0, 0, 0};
        #pragma unroll
        for (int ft = 0; ft < 8; ++ft) {
            int f = ft * 16 + mn;
            float bv = bf2f(bl[f]);
            #pragma unroll
            for (int r = 0; r < 4; ++r) {
                float v = acc[ft][g][r] + bv;
                acc[ft][g][r] = v;
                s1[r] += v; s2[r] += v * v;
            }
        }
        #pragma unroll
        for (int msk = 1; msk < 16; msk <<= 1) {
            #pragma unroll
            for (int r = 0; r < 4; ++r) {
                s1[r] += __shfl_xor(s1[r], msk, 64);
                s2[r] += __shfl_xor(s2[r], msk, 64);
            }
        }
        #pragma unroll
        for (int r = 0; r < 4; ++r) {
            float mu = s1[r] * (1.0f / 128.0f);
            float var = s2[r] * (1.0f / 128.0f) - mu * mu;
            float rs = rsqrtf(fmaxf(var, 0.f) + 1e-5f);
            s1[r] = mu; s2[r] = rs;
        }
        #pragma unroll
        for (int ft = 0; ft < 8; ++ft) {
            int f = ft * 16 + mn;
            float gm = bf2f(gam[f]), bt = bf2f(bet[f]);
            #pragma unroll
            for (int r = 0; r < 4; ++r) {
                float v = (acc[ft][g][r] - s1[r]) * s2[r] * gm + bt;
                u16 hb = f2b(fmaxf(v, 0.f));
                if (FUSE) {
                    int ln = wave * 32 + g * 16 + quad * 4 + r;   // local node
                    AS2[ln * 128 + (((f >> 3) ^ (ln & 15)) << 3) + (f & 7)] = hb;
                } else {
                    int nd = nb + quad * 4 + r;
                    if (nd < NN) AGG[(size_t)nd * HH + f] = hb;
                }
            }
        }
    }

    if (FUSE) {
        // stage Wo (64x128 -> 1024 chunks) into WS; WS reads all done
        bf16x8 wo[4];
        #pragma unroll
        for (int it = 0; it < 4; ++it) {
            int cid = it * 256 + tid;         // 0..1023
            int ft = cid >> 8, kt = (cid >> 6) & 3, q = (cid >> 4) & 3, f16 = cid & 15;
            wo[it] = *(const bf16x8*)(Wo + (size_t)(ft * 16 + f16) * HH + kt * 32 + q * 8);
        }
        #pragma unroll
        for (int it = 0; it < 4; ++it)
            *(bf16x8*)&WS[(size_t)(it * 256 + tid) * 8] = wo[it];
        __syncthreads();   // h3 + Wo staged

        bf16x8 pfr[2][4];
        #pragma unroll
        for (int g = 0; g < 2; ++g) {
            int ln = wave * 32 + g * 16 + mn;
            #pragma unroll
            for (int kt = 0; kt < 4; ++kt)
                pfr[g][kt] = *(const bf16x8*)&AS2[ln * 128 + (((kt * 4 + quad) ^ (ln & 15)) << 3)];
        }
        f32x4 pacc[4][2];
        #pragma unroll
        for (int ft = 0; ft < 4; ++ft)
            #pragma unroll
            for (int g = 0; g < 2; ++g) pacc[ft][g] = (f32x4){0.f, 0.f, 0.f, 0.f};
        #pragma unroll
        for (int ft = 0; ft < 4; ++ft) {
            #pragma unroll
            for (int kt = 0; kt < 4; ++kt) {
                bf16x8 b = *(const bf16x8*)&WS[(ft * 4 + kt) * 512 + laneoff];
                pacc[ft][0] = __builtin_amdgcn_mfma_f32_16x16x32_bf16(pfr[0][kt], b, pacc[ft][0], 0, 0, 0);
                pacc[ft][1] = __builtin_amdgcn_mfma_f32_16x16x32_bf16(pfr[1][kt], b, pacc[ft][1], 0, 0, 0);
            }
        }
        int isf32 = flags[0];
        #pragma unroll
        for (int g = 0; g < 2; ++g) {
            #pragma unroll
            for (int ft = 0; ft < 4; ++ft) {
                int f = ft * 16 + mn;
                float bv = bf2f(bo[f]);
                #pragma unroll
                for (int r = 0; r < 4; ++r) {
                    int nd = n0w + g * 16 + quad * 4 + r;
                    if (nd < NN) {
                        float v = pacc[ft][g][r] + bv;
                        if (isf32) ((float*)out)[(size_t)nd * DOUT + f] = v;
                        else       ((u16*)out)[(size_t)nd * DOUT + f]   = f2b(v);
                    }
                }
            }
        }
    }
}

extern "C" void kernel_launch(void* const* d_in, const int* in_sizes, int n_in,
                              void* d_out, int out_size, void* d_ws, size_t ws_size,
                              hipStream_t stream) {
    const void* xin = d_in[0];
    const void* ei  = d_in[1];     // [2][NE]: row0=src, row1=dst

    u16*   xc     = (u16*)d_ws;                 // NHTOT bf16
    u16*   b0     = xc + NHTOT;                 // NHTOT bf16
    u16*   wc     = b0 + NHTOT;                 // WTOT (padded to 107776)
    float* invdeg = (float*)(wc + 107776);      // NN
    int*   cnt    = (int*)(invdeg + NN);        // NN
    int*   cur    = cnt + NN;                   // NN
    int*   offs   = cur + NN;                   // NN+1
    int*   ssrc   = offs + NN + 1;              // NE
    int*   part   = ssrc + NE;                  // 512 (part[0] = scan global base)
    int*   flags  = part + 512;                 // 2

    // 1: sniff dtypes + zero cnt/gbase
    k_sz<<<1 + SCAN_B, 256, 0, stream>>>((const u16*)xin, (const int*)ei,
                                         flags, cnt, part);
    // 2: merged x-cvt | weight-cvt | degree-hist
    k_prep<<<NB_CVT + NB_CVTW + NB_HIST, 256, 0, stream>>>(
            xin, (uint2*)xc, d_in[2], d_in[3], d_in[4], d_in[5], d_in[6],
            d_in[7], d_in[8], wc, ei, cnt, flags);
    // 3: one-pass offsets (block scan + atomic base; order-free CSR)
    k_offs<<<SCAN_B, 256, 0, stream>>>(cnt, part, offs, cur, invdeg);
    // 4: counting sort
    k_sort<<<(NE + 255) / 256, 256, 0, stream>>>(ei, cur, ssrc, flags);

    const u16* Wl  = wc + OW_Wl;
    const u16* bl  = wc + OW_bl;
    const u16* Wr  = wc + OW_Wr;
    const u16* gam = wc + OW_gam;
    const u16* bet = wc + OW_bet;
    const u16* Wo  = wc + OW_Wo;
    const u16* bo  = wc + OW_bo;

    int ablk = NN * 16 / 256;        // 4 nodes/wave * 4 waves = 16 nodes/block, exact
    int gblk = (NN + 127) / 128;     // 128 nodes per block
    // layer 0: X=xc, agg->b0, gemm in place over b0
    k_agg<<<ablk, 256, 0, stream>>>((const bf16x8*)xc, offs, cnt, ssrc, invdeg, (bf16x8*)b0);
    k_gemm<0><<<gblk, 256, 0, stream>>>(xc, b0, Wl, Wr, bl, gam, bet,
                                        Wo, bo, d_out, flags);
    // layer 1: X=b0, agg->xc, gemm in place over xc (Wr has +I folded)
    k_agg<<<ablk, 256, 0, stream>>>((const bf16x8*)b0, offs, cnt, ssrc, invdeg, (bf16x8*)xc);
    k_gemm<0><<<gblk, 256, 0, stream>>>(b0, xc,
            Wl + HH * HH, Wr + HH * HH, bl + HH, gam + HH, bet + HH,
            Wo, bo, d_out, flags);
    // layer 2 + projection fused: X=xc, agg->b0, out <- proj(LN(...))
    k_agg<<<ablk, 256, 0, stream>>>((const bf16x8*)xc, offs, cnt, ssrc, invdeg, (bf16x8*)b0);
    k_gemm<1><<<gblk, 256, 0, stream>>>(xc, b0,
            Wl + 2 * HH * HH, Wr + 2 * HH * HH, bl + 2 * HH, gam + 2 * HH, bet + 2 * HH,
            Wo, bo, d_out, flags);
}